// Round 4
// baseline (450.224 us; speedup 1.0000x reference)
//
#include <hip/hip_runtime.h>
#include <hip/hip_bf16.h>
#include <stdint.h>

typedef __attribute__((ext_vector_type(8))) short short8;
typedef __attribute__((ext_vector_type(4))) float floatx4;
typedef __attribute__((ext_vector_type(16))) float floatx16;
typedef __attribute__((ext_vector_type(4))) int int4v;
typedef __attribute__((ext_vector_type(4))) unsigned int uint4v;
typedef __attribute__((ext_vector_type(2))) unsigned int uint2v;

#define MFMA16(a, b, c) __builtin_amdgcn_mfma_f32_16x16x32_bf16(a, b, c, 0, 0, 0)
#define MFMA32(a, b, c) __builtin_amdgcn_mfma_f32_32x32x16_bf16(a, b, c, 0, 0, 0)

static constexpr int kHW = 4096;
static constexpr int kC  = 256;
static constexpr int kD  = 32;
static constexpr int kDV = 128;

__device__ __forceinline__ short f2bf(float f) {
  union { float f; uint32_t u; } v; v.f = f;
  uint32_t r = (v.u + 0x7FFFu + ((v.u >> 16) & 1u)) >> 16;  // RNE
  return (short)(uint16_t)r;
}
__device__ __forceinline__ float bf2f(short s) {
  union { uint32_t u; float f; } v; v.u = ((uint32_t)(uint16_t)s) << 16;
  return v.f;
}
__device__ __forceinline__ void split_bf(float f, short& hi, short& lo) {
  hi = f2bf(f);
  lo = f2bf(f - bf2f(hi));
}
__device__ __forceinline__ uint32_t fbits(float f) {
  union { float f; uint32_t u; } v; v.f = f; return v.u;
}
// pack two floats to bf16x2 (even in low half), round-half-up via +0x8000
__device__ __forceinline__ uint32_t pk2(float e, float o) {
  return __builtin_amdgcn_perm(fbits(o) + 0x8000u, fbits(e) + 0x8000u, 0x07060302u);
}
__device__ __forceinline__ short8 mkfrag(uint32_t a, uint32_t b, uint32_t c, uint32_t d) {
  uint4v t = {a, b, c, d};
  return __builtin_bit_cast(short8, t);
}

// ---------------------------------------------------------------------------
// Kernel 0: one-time weight prep.  Split fp32 -> (hi,lo) bf16, transposed.
// ---------------------------------------------------------------------------
__global__ __launch_bounds__(256) void prep_kernel(
    const float* __restrict__ Wf, const float* __restrict__ Wg,
    const float* __restrict__ Wh, const float* __restrict__ Wo,
    short* __restrict__ Wt_h, short* __restrict__ Wt_l,
    short* __restrict__ Wot_h, short* __restrict__ Wot_l) {
  const int i = blockIdx.x * 256 + threadIdx.x;
  const int total1 = 192 * 256;
  if (i < total1) {
    int c = i >> 8, k = i & 255;
    float wv;
    if (c < 32)       wv = Wf[(size_t)k * 32 + c];
    else if (c < 64)  wv = Wg[(size_t)k * 32 + (c - 32)];
    else              wv = Wh[(size_t)k * 128 + (c - 64)];
    short h, l; split_bf(wv, h, l);
    Wt_h[i] = h; Wt_l[i] = l;
  } else {
    int j = i - total1;
    int c = j >> 7, k = j & 127;
    short h, l; split_bf(Wo[(size_t)k * 256 + c], h, l);
    Wot_h[j] = h; Wot_l[j] = l;
  }
}

// ---------------------------------------------------------------------------
// Kernel 1: f,g,h projections (split-bf16).  64 px/block, grid 1024 -> 4
// blocks/CU for latency hiding.  Weights direct from L1/L2.
// ---------------------------------------------------------------------------
__global__ __launch_bounds__(256, 4) void fgh_kernel(
    const float* __restrict__ x,
    const float* __restrict__ bfv, const float* __restrict__ bgv,
    const float* __restrict__ bhv,
    const short* __restrict__ Wt_h, const short* __restrict__ Wt_l,
    short* __restrict__ f_h, short* __restrict__ f_l,
    short* __restrict__ g_h, short* __restrict__ g_l,
    short* __restrict__ hT) {
  __shared__ short ht2[128][72];   // [dv][px] transpose buffer, 18.4 KB

  const int tid  = threadIdx.x;
  const int lane = tid & 63;
  const int w    = tid >> 6;
  const int cl   = lane & 15;
  const int row4 = lane >> 4;
  const int px0  = blockIdx.x * 64;

  floatx4 acc[12];
#pragma unroll
  for (int i = 0; i < 12; ++i) acc[i] = (floatx4){0.f, 0.f, 0.f, 0.f};

#pragma unroll
  for (int kp = 0; kp < 8; ++kp) {
    const float* xr = x + (size_t)(px0 + w * 16 + cl) * kC + kp * 32 + row4 * 8;
    float4 v0 = *reinterpret_cast<const float4*>(xr);
    float4 v1 = *reinterpret_cast<const float4*>(xr + 4);
    float vv[8] = {v0.x, v0.y, v0.z, v0.w, v1.x, v1.y, v1.z, v1.w};
    short8 xh, xl;
#pragma unroll
    for (int e = 0; e < 8; ++e) {
      short h, l; split_bf(vv[e], h, l);
      xh[e] = h; xl[e] = l;
    }
#pragma unroll
    for (int ct = 0; ct < 12; ++ct) {
      const size_t woff = (size_t)(ct * 16 + cl) * 256 + kp * 32 + row4 * 8;
      short8 bh_ = *reinterpret_cast<const short8*>(Wt_h + woff);
      short8 bl_ = *reinterpret_cast<const short8*>(Wt_l + woff);
      acc[ct] = MFMA16(xh, bh_, acc[ct]);
      acc[ct] = MFMA16(xh, bl_, acc[ct]);
      acc[ct] = MFMA16(xl, bh_, acc[ct]);
    }
  }

  // f and g: split hi/lo stores
#pragma unroll
  for (int ct = 0; ct < 4; ++ct) {
    int c = ct * 16 + cl;
    float bias = (c < 32) ? bfv[c] : bgv[c - 32];
    const int cc = (c < 32) ? c : (c - 32);
    short* dh = (c < 32) ? f_h : g_h;
    short* dl = (c < 32) ? f_l : g_l;
#pragma unroll
    for (int j = 0; j < 4; ++j) {
      int pix = px0 + w * 16 + row4 * 4 + j;
      short h, l; split_bf(acc[ct][j] + bias, h, l);
      dh[(size_t)pix * kD + cc] = h;
      dl[(size_t)pix * kD + cc] = l;
    }
  }

  // h: transpose via LDS, write hT[b][dv][pix] coalesced
#pragma unroll
  for (int ct = 4; ct < 12; ++ct) {
    int dv = (ct - 4) * 16 + cl;
    float bias = bhv[dv];
#pragma unroll
    for (int j = 0; j < 4; ++j)
      ht2[dv][w * 16 + row4 * 4 + j] = f2bf(acc[ct][j] + bias);
  }
  __syncthreads();
  const int b   = px0 >> 12;
  const int pb0 = px0 & 4095;
#pragma unroll
  for (int it = 0; it < 4; ++it) {
    int c = tid + it * 256;          // 0..1023 16B-chunks
    int dv = c >> 3, p8 = c & 7;
    int4v v = *reinterpret_cast<const int4v*>(&ht2[dv][p8 * 8]);
    *reinterpret_cast<int4v*>(hT + ((size_t)(b * kDV + dv)) * kHW + pb0 + p8 * 8) = v;
  }
}

// ---------------------------------------------------------------------------
// Kernel 2: flash attention, swapped-operand 32x32 MFMA, double-buffered V.
// Block = 1 batch x 128 queries, 256 thr (4 waves x 32 queries each).
// One barrier per 128-key tile; V staged global->reg->LDS (alternate buffer).
// ---------------------------------------------------------------------------
__global__ __launch_bounds__(256, 2) void attn_kernel(
    const short* __restrict__ fkh, const short* __restrict__ fkl,
    const short* __restrict__ gqh, const short* __restrict__ gql,
    const short* __restrict__ hT,
    short* __restrict__ og) {
  __shared__ __align__(16) char smem[65536];  // 2 x 32KB V buffers; epilogue reuse

  const int tid  = threadIdx.x;
  const int lane = tid & 63;
  const int w    = tid >> 6;       // 0..3
  const int cl   = lane & 31;
  const int hi   = lane >> 5;      // 0..1
  const int bb   = blockIdx.x >> 5;
  const int q0   = (blockIdx.x & 31) * 128;
  const int qw   = q0 + w * 32;

  const int  sdv  = tid >> 4;            // staging: dv row this thread covers
  const int  sk16 = tid & 15;            // 16B chunk within row
  const short* hTb = hT + (size_t)bb * kDV * kHW;

  const size_t qbase = ((size_t)bb * kHW + qw + cl) * kD + hi * 8;
  const short8 qh0 = *reinterpret_cast<const short8*>(gqh + qbase);
  const short8 qh1 = *reinterpret_cast<const short8*>(gqh + qbase + 16);
  const short8 ql0 = *reinterpret_cast<const short8*>(gql + qbase);
  const short8 ql1 = *reinterpret_cast<const short8*>(gql + qbase + 16);

  const floatx16 z16 = {0.f,0.f,0.f,0.f,0.f,0.f,0.f,0.f,0.f,0.f,0.f,0.f,0.f,0.f,0.f,0.f};
  floatx16 acc[4];
#pragma unroll
  for (int i = 0; i < 4; ++i) acc[i] = z16;
  float m = -1e30f, ls = 0.f;

  uint4v vr[8];
  // prologue: tile0 -> buf0; issue tile1 loads
#pragma unroll
  for (int it = 0; it < 8; ++it) {
    int dv = sdv + it * 16;
    vr[it] = *reinterpret_cast<const uint4v*>(hTb + (size_t)dv * kHW + 0 * 128 + sk16 * 8);
  }
#pragma unroll
  for (int it = 0; it < 8; ++it) {
    int dv = sdv + it * 16;
    *reinterpret_cast<uint4v*>(smem + dv * 256 + ((sk16 * 16) ^ ((dv & 15) << 4))) = vr[it];
  }
#pragma unroll
  for (int it = 0; it < 8; ++it) {
    int dv = sdv + it * 16;
    vr[it] = *reinterpret_cast<const uint4v*>(hTb + (size_t)dv * kHW + 1 * 128 + sk16 * 8);
  }
  __syncthreads();

  for (int kb = 0; kb < 32; ++kb) {
    char* Vb = smem + (kb & 1) * 32768;
    if (kb + 1 < 32) {
      char* Vn = smem + ((kb + 1) & 1) * 32768;
#pragma unroll
      for (int it = 0; it < 8; ++it) {
        int dv = sdv + it * 16;
        *reinterpret_cast<uint4v*>(Vn + dv * 256 + ((sk16 * 16) ^ ((dv & 15) << 4))) = vr[it];
      }
      if (kb + 2 < 32) {
#pragma unroll
        for (int it = 0; it < 8; ++it) {
          int dv = sdv + it * 16;
          vr[it] = *reinterpret_cast<const uint4v*>(
              hTb + (size_t)dv * kHW + (kb + 2) * 128 + sk16 * 8);
        }
      }
    }

#pragma unroll
    for (int t = 0; t < 4; ++t) {    // 4 x 32-key S-tiles
      const int kk = kb * 128 + t * 32;
      const size_t kbse = ((size_t)bb * kHW + kk + cl) * kD + hi * 8;
      short8 kh0 = *reinterpret_cast<const short8*>(fkh + kbse);
      short8 kh1 = *reinterpret_cast<const short8*>(fkh + kbse + 16);
      short8 kl0 = *reinterpret_cast<const short8*>(fkl + kbse);
      short8 kl1 = *reinterpret_cast<const short8*>(fkl + kbse + 16);

      floatx16 s = MFMA32(kh0, qh0, z16);
      s = MFMA32(kh1, qh1, s);
      s = MFMA32(kl0, qh0, s);
      s = MFMA32(kl1, qh1, s);
      s = MFMA32(kh0, ql0, s);
      s = MFMA32(kh1, ql1, s);

      float tm = fmaxf(fmaxf(s[0], s[1]), fmaxf(s[2], s[3]));
      tm = fmaxf(tm, fmaxf(fmaxf(s[4], s[5]), fmaxf(s[6], s[7])));
      float tm2 = fmaxf(fmaxf(s[8], s[9]), fmaxf(s[10], s[11]));
      tm2 = fmaxf(tm2, fmaxf(fmaxf(s[12], s[13]), fmaxf(s[14], s[15])));
      tm = fmaxf(tm, tm2);
      tm = fmaxf(tm, __shfl_xor(tm, 32));

      if (__any(tm > m + 8.0f)) {    // T13 defer-max
        float mn = fmaxf(m, tm);
        float sc = __expf(m - mn);
        ls *= sc;
#pragma unroll
        for (int ct = 0; ct < 4; ++ct)
#pragma unroll
          for (int r = 0; r < 16; ++r) acc[ct][r] *= sc;
        m = mn;
      }

      float pr[16];
      float sum = 0.f;
#pragma unroll
      for (int r = 0; r < 16; ++r) {
        pr[r] = __expf(s[r] - m);
        sum += pr[r];
      }
      ls += sum;

      // pack P^T pairs -> bf16x2 words, then permlane32_swap to build B-frags
      uint32_t pk[8];
#pragma unroll
      for (int i = 0; i < 8; ++i) pk[i] = pk2(pr[2 * i], pr[2 * i + 1]);
      {
        uint2v r0 = __builtin_amdgcn_permlane32_swap(pk[0], pk[2], false, false);
        pk[0] = r0.x; pk[2] = r0.y;
        uint2v r1 = __builtin_amdgcn_permlane32_swap(pk[1], pk[3], false, false);
        pk[1] = r1.x; pk[3] = r1.y;
        uint2v r2 = __builtin_amdgcn_permlane32_swap(pk[4], pk[6], false, false);
        pk[4] = r2.x; pk[6] = r2.y;
        uint2v r3 = __builtin_amdgcn_permlane32_swap(pk[5], pk[7], false, false);
        pk[5] = r3.x; pk[7] = r3.y;
      }
      short8 pf0 = mkfrag(pk[0], pk[1], pk[2], pk[3]);
      short8 pf1 = mkfrag(pk[4], pk[5], pk[6], pk[7]);

      // O^T += V^T P^T
      __builtin_amdgcn_s_setprio(1);
#pragma unroll
      for (int ct = 0; ct < 4; ++ct) {
        int dv = ct * 32 + cl;
        short8 va = *reinterpret_cast<const short8*>(
            Vb + dv * 256 + (((t * 2 + 0) * 32 + hi * 16) ^ ((dv & 15) << 4)));
        acc[ct] = MFMA32(va, pf0, acc[ct]);
      }
#pragma unroll
      for (int ct = 0; ct < 4; ++ct) {
        int dv = ct * 32 + cl;
        short8 va = *reinterpret_cast<const short8*>(
            Vb + dv * 256 + (((t * 2 + 1) * 32 + hi * 16) ^ ((dv & 15) << 4)));
        acc[ct] = MFMA32(va, pf1, acc[ct]);
      }
      __builtin_amdgcn_s_setprio(0);
    }
    __syncthreads();   // all reads of Vb done; writers may reuse next iter
  }

  ls += __shfl_xor(ls, 32);
  const float inv = 1.0f / ls;

  // epilogue: O^T -> [q][dv] via LDS, coalesced global store
  short* ot = reinterpret_cast<short*>(smem) + w * 32 * 136;
#pragma unroll
  for (int ct = 0; ct < 4; ++ct)
#pragma unroll
    for (int r = 0; r < 16; ++r) {
      int dv = ct * 32 + (r & 3) + 8 * (r >> 2) + 4 * hi;
      ot[cl * 136 + dv] = f2bf(acc[ct][r] * inv);
    }
  __syncthreads();
#pragma unroll
  for (int it = 0; it < 8; ++it) {
    int q2 = it * 4 + (lane >> 4);
    int ck = lane & 15;
    int4v v = *reinterpret_cast<const int4v*>(ot + q2 * 136 + ck * 8);
    *reinterpret_cast<int4v*>(og + ((size_t)bb * kHW + qw + q2) * kDV + ck * 8) = v;
  }
}

// ---------------------------------------------------------------------------
// Kernel 3: out = x + o @ Wo + bo.  Pre-split Wo^T fragments direct from L2.
// ---------------------------------------------------------------------------
__global__ __launch_bounds__(256, 4) void outproj_kernel(
    const short* __restrict__ o,
    const short* __restrict__ Wot_h, const short* __restrict__ Wot_l,
    const float* __restrict__ bo,
    const float* __restrict__ x,
    float* __restrict__ out) {
  const int tid  = threadIdx.x;
  const int lane = tid & 63;
  const int w    = tid >> 6;
  const int cl   = lane & 15;
  const int row4 = lane >> 4;
  const int px0  = blockIdx.x * 64;

  floatx4 acc[16];
#pragma unroll
  for (int i = 0; i < 16; ++i) acc[i] = (floatx4){0.f, 0.f, 0.f, 0.f};

#pragma unroll
  for (int kp = 0; kp < 4; ++kp) {
    short8 a = *reinterpret_cast<const short8*>(
        o + (size_t)(px0 + w * 16 + cl) * kDV + kp * 32 + row4 * 8);
#pragma unroll
    for (int ct = 0; ct < 16; ++ct) {
      const size_t woff = (size_t)(ct * 16 + cl) * 128 + kp * 32 + row4 * 8;
      short8 bh_ = *reinterpret_cast<const short8*>(Wot_h + woff);
      short8 bl_ = *reinterpret_cast<const short8*>(Wot_l + woff);
      acc[ct] = MFMA16(a, bh_, acc[ct]);
      acc[ct] = MFMA16(a, bl_, acc[ct]);
    }
  }

#pragma unroll
  for (int ct = 0; ct < 16; ++ct) {
    int c = ct * 16 + cl;
    float bias = bo[c];
#pragma unroll
    for (int j = 0; j < 4; ++j) {
      size_t idx = (size_t)(px0 + w * 16 + row4 * 4 + j) * kC + c;
      out[idx] = x[idx] + acc[ct][j] + bias;
    }
  }
}

// ---------------------------------------------------------------------------
extern "C" void kernel_launch(void* const* d_in, const int* in_sizes, int n_in,
                              void* d_out, int out_size, void* d_ws, size_t ws_size,
                              hipStream_t stream) {
  const float* x  = (const float*)d_in[0];
  const float* Wf = (const float*)d_in[1];
  const float* bf = (const float*)d_in[2];
  const float* Wg = (const float*)d_in[3];
  const float* bg = (const float*)d_in[4];
  const float* Wh = (const float*)d_in[5];
  const float* bh = (const float*)d_in[6];
  const float* Wo = (const float*)d_in[7];
  const float* bo = (const float*)d_in[8];
  float* out = (float*)d_out;

  char* ws = (char*)d_ws;
  const size_t MB = 1024 * 1024;
  short* f_h = (short*)(ws);             //  4 MB  [65536][32] bf16
  short* f_l = (short*)(ws + 4  * MB);   //  4 MB
  short* g_h = (short*)(ws + 8  * MB);   //  4 MB
  short* g_l = (short*)(ws + 12 * MB);   //  4 MB
  short* hT  = (short*)(ws + 16 * MB);   // 16 MB  [16][128][4096] bf16
  short* o   = (short*)(ws + 32 * MB);   // 16 MB  [65536][128] bf16
  short* Wt_h  = (short*)(ws + 48 * MB);            //  96 KB [192][256]
  short* Wt_l  = (short*)(ws + 48 * MB + 98304);    //  96 KB
  short* Wot_h = (short*)(ws + 48 * MB + 196608);   //  64 KB [256][128]
  short* Wot_l = (short*)(ws + 48 * MB + 262144);   //  64 KB

  prep_kernel<<<320, 256, 0, stream>>>(Wf, Wg, Wh, Wo, Wt_h, Wt_l, Wot_h, Wot_l);
  fgh_kernel<<<1024, 256, 0, stream>>>(x, bf, bg, bh, Wt_h, Wt_l,
                                       f_h, f_l, g_h, g_l, hT);
  attn_kernel<<<512, 256, 0, stream>>>(f_h, f_l, g_h, g_l, hT, o);
  outproj_kernel<<<1024, 256, 0, stream>>>(o, Wot_h, Wot_l, bo, x, out);
}